// Round 2
// baseline (236.449 us; speedup 1.0000x reference)
//
#include <hip/hip_runtime.h>

// patches [B,N,L] fp32; masked_indices [B,M] int64 in ref -> passed as int per
// harness convention ("integer -> const int*"). Values are in [0, N).
constexpr int B = 256;
constexpr int N = 1024;
constexpr int L = 128;     // row = 128 floats = 32 float4 = 512 B
constexpr int M = 512;
constexpr int SPLIT = 4;   // blocks per batch
constexpr int BLOCK = 256;

// Single fused kernel: per-batch flag table in LDS, then copy-or-linspace.
__global__ __launch_bounds__(BLOCK) void fused_kernel(
        const float* __restrict__ in,
        const int* __restrict__ idx,
        float* __restrict__ out) {
    const int b    = blockIdx.x / SPLIT;
    const int part = blockIdx.x % SPLIT;

    __shared__ unsigned char flags[N];
    // Zero the flag table (N=1024 bytes, 256 threads -> 4 each).
    for (int i = threadIdx.x; i < N; i += BLOCK) flags[i] = 0;
    __syncthreads();
    // Scatter this batch's masked indices (M=512 -> 2 per thread).
    // Duplicates write the same value; no hazard.
    for (int i = threadIdx.x; i < M; i += BLOCK) flags[idx[b * M + i]] = 1;
    __syncthreads();

    const float* bin  = in  + (size_t)b * (N * L);
    float*       bout = out + (size_t)b * (N * L);

    constexpr int QUADS_PER_BATCH = N * L / 4;           // 32768
    constexpr int QUADS_PER_PART  = QUADS_PER_BATCH / SPLIT; // 8192
    const int base = part * QUADS_PER_PART;

    for (int i = threadIdx.x; i < QUADS_PER_PART; i += BLOCK) {
        const int q    = base + i;
        const int row  = q >> 5;   // row within batch
        const int quad = q & 31;   // float4 index within row
        const float* rowp = bin + row * L;
        float4 v;
        if (flags[row]) {
            // linspace(row[0], row[127], 128): s + (e-s) * (l/127)
            const float s = rowp[0];
            const float d = rowp[L - 1] - s;
            const int l0 = quad * 4;
            v.x = fmaf(d, (float)(l0 + 0) * (1.0f / 127.0f), s);
            v.y = fmaf(d, (float)(l0 + 1) * (1.0f / 127.0f), s);
            v.z = fmaf(d, (float)(l0 + 2) * (1.0f / 127.0f), s);
            v.w = fmaf(d, (float)(l0 + 3) * (1.0f / 127.0f), s);
        } else {
            v = ((const float4*)bin)[q];
        }
        ((float4*)bout)[q] = v;
    }
}

extern "C" void kernel_launch(void* const* d_in, const int* in_sizes, int n_in,
                              void* d_out, int out_size, void* d_ws, size_t ws_size,
                              hipStream_t stream) {
    const float* patches = (const float*)d_in[0];
    const int* masked    = (const int*)d_in[1];
    float* out           = (float*)d_out;

    fused_kernel<<<B * SPLIT, BLOCK, 0, stream>>>(patches, masked, out);
}

// Round 4
// 233.302 us; speedup vs baseline: 1.0135x; 1.0135x over previous
//
#include <hip/hip_runtime.h>

// patches [B,N,L] fp32; masked_indices [B,M]; values in [0, N).
constexpr int B = 256;
constexpr int N = 1024;
constexpr int L = 128;     // row = 128 floats = 32 float4 = 512 B
constexpr int M = 512;
constexpr int SPLIT = 8;   // blocks per batch
constexpr int BLOCK = 256;

// Native vector type — __builtin_nontemporal_* requires scalar/native-vector
// pointee (HIP_vector_type<float,4> is a struct and is rejected).
typedef float vfloat4 __attribute__((ext_vector_type(4)));

// Single fused kernel: per-batch flag table in LDS, then copy-or-linspace.
// Output is written exactly once and never re-read -> non-temporal stores.
// Input copy path is read-once -> non-temporal loads.
__global__ __launch_bounds__(BLOCK) void fused_kernel(
        const float* __restrict__ in,
        const int* __restrict__ idx,
        float* __restrict__ out) {
    const int b    = blockIdx.x / SPLIT;
    const int part = blockIdx.x % SPLIT;

    __shared__ unsigned char flags[N];
    for (int i = threadIdx.x; i < N; i += BLOCK) flags[i] = 0;
    __syncthreads();
    // Duplicates write the same value; no hazard.
    for (int i = threadIdx.x; i < M; i += BLOCK) flags[idx[b * M + i]] = 1;
    __syncthreads();

    const float* bin  = in  + (size_t)b * (N * L);
    float*       bout = out + (size_t)b * (N * L);

    constexpr int QUADS_PER_BATCH = N * L / 4;               // 32768
    constexpr int QUADS_PER_PART  = QUADS_PER_BATCH / SPLIT; // 4096
    const int base = part * QUADS_PER_PART;

    for (int i = threadIdx.x; i < QUADS_PER_PART; i += BLOCK) {
        const int q    = base + i;
        const int row  = q >> 5;   // row within batch
        const int quad = q & 31;   // float4 index within row
        const float* rowp = bin + row * L;
        vfloat4 v;
        if (flags[row]) {
            // linspace(row[0], row[127], 128): s + (e-s) * (l/127)
            const float s = rowp[0];
            const float d = rowp[L - 1] - s;
            const int l0 = quad * 4;
            v.x = fmaf(d, (float)(l0 + 0) * (1.0f / 127.0f), s);
            v.y = fmaf(d, (float)(l0 + 1) * (1.0f / 127.0f), s);
            v.z = fmaf(d, (float)(l0 + 2) * (1.0f / 127.0f), s);
            v.w = fmaf(d, (float)(l0 + 3) * (1.0f / 127.0f), s);
        } else {
            v = __builtin_nontemporal_load(((const vfloat4*)bin) + q);
        }
        __builtin_nontemporal_store(v, ((vfloat4*)bout) + q);
    }
}

extern "C" void kernel_launch(void* const* d_in, const int* in_sizes, int n_in,
                              void* d_out, int out_size, void* d_ws, size_t ws_size,
                              hipStream_t stream) {
    const float* patches = (const float*)d_in[0];
    const int* masked    = (const int*)d_in[1];
    float* out           = (float*)d_out;

    fused_kernel<<<B * SPLIT, BLOCK, 0, stream>>>(patches, masked, out);
}